// Round 1
// baseline (155.390 us; speedup 1.0000x reference)
//
#include <hip/hip_runtime.h>
#include <math.h>

#define N 256
#define G 2            // systems per block (was 4): 512 blocks -> 2 blocks/CU
#define BLK 512        // 8 waves; each wave owns 2 row-panels of S
#define S1 10          // Krylov steps, sweep 1
#define S2 8           // Krylov steps, sweep 2
#define SP1 11         // S1+1
#define VS 268         // f32 K row stride (words), 16B-aligned
#define UTS 280        // f16 uT row stride
#define RIDGE 3e-5f

typedef _Float16 half8v __attribute__((ext_vector_type(8)));
typedef float float4v __attribute__((ext_vector_type(4)));

// ---- LDS arena (bytes), 16-aligned ----
#define OFF_K     0          // SP1*G*VS*4 = 23584 : K[(i*G+g)*VS + c]
#define OFF_UT0   23584      // G*UTS*2 = 1120 : f16 u staging, buffer 0
#define OFF_UT1   24704      // 1120 : buffer 1
#define OFF_ZTW   25824      // 8*128*4 = 4096 : MFMA out staging (2 panels/wave)
#define OFF_GRAM  29920      // SP1*SP1*G*4 = 968 (+pad)
#define OFF_L     30896      // S1*S1*G*4 = 800
#define OFF_D     31696      // S1*G*4 = 80
#define ARENA_SZ  31776

// B-fragment read: lane provides B[k=32t+8mq+j][n=mn]; systems in rows 0..1,
// (mn&1) duplicates them across cols (broadcast-friendly).
#define LD_FRAG(base, t) (*(const half8v*)((base) + (mn & 1) * UTS + 32 * (t) + 8 * mq))

// zm = (S (x.*q))[c] for this thread's (c,g); q staged f16 at basep.
// Each wave computes 2 panels (rows 32wv..32wv+15, 32wv+16..32wv+31) off the
// SAME 8 B-fragments; wave-local LDS round-trip redistributes to solver lanes.
#define MATVEC(basep, dst) do {                                                            \
    float4v a00 = {0.f,0.f,0.f,0.f}, a01 = {0.f,0.f,0.f,0.f};                              \
    float4v a10 = {0.f,0.f,0.f,0.f}, a11 = {0.f,0.f,0.f,0.f};                              \
    _Pragma("unroll")                                                                      \
    for (int t = 0; t < 4; ++t) {                                                          \
        half8v b0 = LD_FRAG(basep, t);                                                     \
        half8v b1 = LD_FRAG(basep, t + 4);                                                 \
        a00 = __builtin_amdgcn_mfma_f32_16x16x32_f16(Shi[t],      b0, a00, 0, 0, 0);       \
        a10 = __builtin_amdgcn_mfma_f32_16x16x32_f16(Shi[8 + t],  b0, a10, 0, 0, 0);       \
        a01 = __builtin_amdgcn_mfma_f32_16x16x32_f16(Shi[4 + t],  b1, a01, 0, 0, 0);       \
        a11 = __builtin_amdgcn_mfma_f32_16x16x32_f16(Shi[12 + t], b1, a11, 0, 0, 0);       \
    }                                                                                      \
    float4v s0v = a00 + a01, s1v = a10 + a11;                                              \
    if (mn < 2) {                                                                          \
        *(float4v*)(zTw + wv * 128 + mn * 16 + mq * 4) = s0v;                              \
        *(float4v*)(zTw + wv * 128 + 64 + mn * 16 + mq * 4) = s1v;                         \
    }                                                                                      \
    dst = zTw[wv * 128 + (lane >> 5) * 64 + g * 16 + ((lane >> 1) & 15)];                  \
} while (0)

// CA-GMRES + fp32 IR with SHIFTED Newton basis: k_{i+1} = 0.5*Sx*k_i (spectral
// center of A = I + Sx removed -> far better Gram conditioning than A-powers).
// Arnoldi-free identity: A k_i = k_i + 2 k_{i+1}. LSQ matrix = (1,2,2,4)-stencil
// of the Gram matrix; per-system ridge-Cholesky; fp32 residual between sweeps.
// v13: G=4 -> G=2 so the grid becomes 512 blocks = 2 independent barrier
// domains per CU; chain stalls of one block are filled by the other.
__global__ __launch_bounds__(BLK, 4) void cayley_v13(const float* __restrict__ x_all,
                                                     const float* __restrict__ P,
                                                     const float* __restrict__ v_in,
                                                     float* __restrict__ out, int batch) {
    __shared__ __align__(16) char arena[ARENA_SZ];
    float* sK      = (float*)(arena + OFF_K);
    _Float16* uT0  = (_Float16*)(arena + OFF_UT0);
    _Float16* uT1  = (_Float16*)(arena + OFF_UT1);
    float* zTw     = (float*)(arena + OFF_ZTW);
    float* sGram   = (float*)(arena + OFF_GRAM);
    float* sL      = (float*)(arena + OFF_L);
    float* sD      = (float*)(arena + OFF_D);

    const int tid = threadIdx.x;
    const int lane = tid & 63, wv = tid >> 6;
    const int mn = lane & 15, mq = lane >> 4;        // MFMA fragment coords
    const int c = tid >> 1, g = tid & 1;             // solver coords
    const int sys = blockIdx.x * G + g;
    const bool alive = sys < batch;

    // ---- preamble: S = P - P^T rows [32wv,32wv+32) as f16 A-fragments ----
    half8v Shi[16];
#pragma unroll
    for (int p = 0; p < 2; ++p) {
        const int r = 32 * wv + 16 * p + mn;
#pragma unroll
        for (int t = 0; t < 8; ++t) {
            const int k0 = 32 * t + 8 * mq;
            float4v pa = *(const float4v*)(P + r * N + k0);
            float4v pb = *(const float4v*)(P + r * N + k0 + 4);
            half8v hi;
            hi[0] = (_Float16)(pa.x - P[(k0 + 0) * N + r]);
            hi[1] = (_Float16)(pa.y - P[(k0 + 1) * N + r]);
            hi[2] = (_Float16)(pa.z - P[(k0 + 2) * N + r]);
            hi[3] = (_Float16)(pa.w - P[(k0 + 3) * N + r]);
            hi[4] = (_Float16)(pb.x - P[(k0 + 4) * N + r]);
            hi[5] = (_Float16)(pb.y - P[(k0 + 5) * N + r]);
            hi[6] = (_Float16)(pb.z - P[(k0 + 6) * N + r]);
            hi[7] = (_Float16)(pb.w - P[(k0 + 7) * N + r]);
            Shi[p * 8 + t] = hi;
        }
    }

    const float x_own = alive ? x_all[sys * N + c] : 0.f;
    const float v_own = v_in[c];
    float wsol = 0.f;

    for (int sw = 0; sw < 2; ++sw) {
        const int s = sw ? S2 : S1;

        // ---- k_0 = fp32 residual through the f16 operator ----
        float kq;
        if (sw == 0) {
            kq = alive ? v_own : 0.f;
        } else {
            uT1[g * UTS + c] = (_Float16)(x_own * wsol);
            __syncthreads();
            float zm;
            MATVEC(uT1, zm);
            kq = alive ? (v_own - wsol - zm) : 0.f;
            // writing uT0 below is safe: laggards read uT1/zTw-own-slot only
        }
        sK[g * VS + c] = kq;
        uT0[g * UTS + c] = (_Float16)(x_own * kq);
        __syncthreads();                                   // buf0 + k_0 visible

        // ---- basis build: k_{i} = 0.5 * Sx k_{i-1}; 1 barrier/step ----
        for (int i = 1; i <= s; ++i) {
            float zm;
            if (i & 1) { MATVEC(uT0, zm); } else { MATVEC(uT1, zm); }
            kq = 0.5f * zm;                                // shifted+scaled basis
            sK[(i * G + g) * VS + c] = kq;
            if (i < s) {
                _Float16* dst = (i & 1) ? uT1 : uT0;
                dst[g * UTS + c] = (_Float16)(x_own * kq);
            }
            __syncthreads();
        }

        // ---- Gram pass: all pairs i<=j; 2 pairs/wave/iter (2 systems each) ----
        const int NP = (s + 1) * (s + 2) / 2;
        {
            const int hf = lane >> 5;                 // which pair within wave
            const int q16 = lane & 15;
            const int gq = (lane >> 4) & 1;           // system within half
            for (int pp = wv * 2 + hf; pp < NP; pp += 16) {
                int i = 0, rem = pp;
                while (rem >= (s + 1 - i)) { rem -= (s + 1 - i); ++i; }
                const int j = i + rem;
                const float* ka = sK + (i * G + gq) * VS + 16 * q16;
                const float* kb = sK + (j * G + gq) * VS + 16 * q16;
                float p;
                {
                    float4v a0 = *(const float4v*)(ka);
                    float4v b0 = *(const float4v*)(kb);
                    float4v a1 = *(const float4v*)(ka + 4);
                    float4v b1 = *(const float4v*)(kb + 4);
                    p = a0.x * b0.x;
                    p = fmaf(a0.y, b0.y, p); p = fmaf(a0.z, b0.z, p); p = fmaf(a0.w, b0.w, p);
                    p = fmaf(a1.x, b1.x, p); p = fmaf(a1.y, b1.y, p);
                    p = fmaf(a1.z, b1.z, p); p = fmaf(a1.w, b1.w, p);
                }
                {
                    float4v a0 = *(const float4v*)(ka + 8);
                    float4v b0 = *(const float4v*)(kb + 8);
                    float4v a1 = *(const float4v*)(ka + 12);
                    float4v b1 = *(const float4v*)(kb + 12);
                    p = fmaf(a0.x, b0.x, p); p = fmaf(a0.y, b0.y, p);
                    p = fmaf(a0.z, b0.z, p); p = fmaf(a0.w, b0.w, p);
                    p = fmaf(a1.x, b1.x, p); p = fmaf(a1.y, b1.y, p);
                    p = fmaf(a1.z, b1.z, p); p = fmaf(a1.w, b1.w, p);
                }
                p += __shfl_xor(p, 1); p += __shfl_xor(p, 2);
                p += __shfl_xor(p, 4); p += __shfl_xor(p, 8);
                if (q16 == 0) {
                    sGram[(i * SP1 + j) * G + gq] = p;
                    if (i != j) sGram[(j * SP1 + i) * G + gq] = p;
                }
            }
        }
        __syncthreads();

        // ---- per-system LSQ: B = (1,2,2,4)-stencil of Gram; solve
        // (Bhat + ridge) chat = rhs_hat via wave-parallel Cholesky ----
        if (wv < G) {
            const int gq = wv;
            const int rr = lane;
#define GG(i, j) sGram[((i) * SP1 + (j)) * G + gq]
            float invn_r = 0.f;
            if (rr < s) {
                const float Brr = GG(rr, rr) + 4.f * GG(rr, rr + 1)
                                + 4.f * GG(rr + 1, rr + 1);
                invn_r = (Brr > 1e-30f) ? (1.f / sqrtf(Brr)) : 0.f;
            }
            for (int k = 0; k < s; ++k) {
                const float invn_k = __shfl(invn_r, k);
                float a = 0.f;
                if (rr >= k && rr < s) {
                    if (rr == k) {
                        a = 1.f + RIDGE;
                    } else {
                        const float Brk = GG(rr, k) + 2.f * GG(rr, k + 1)
                                        + 2.f * GG(rr + 1, k) + 4.f * GG(rr + 1, k + 1);
                        a = Brk * invn_r * invn_k;
                    }
                    for (int m = 0; m < k; ++m)
                        a = fmaf(-sL[(rr * S1 + m) * G + gq],
                                 sL[(k * S1 + m) * G + gq], a);
                }
                float dk = __shfl(a, k);
                dk = fmaxf(dk, 0.5f * RIDGE);
                const float invd = 1.f / sqrtf(dk);
                if (rr >= k && rr < s) sL[(rr * S1 + k) * G + gq] = a * invd;
            }
            // forward solve L t = rhs_hat
            float trr = 0.f, acc = 0.f;
            const float rhs = (rr < s)
                ? (GG(rr, 0) + 2.f * GG(rr + 1, 0)) * invn_r : 0.f;
#undef GG
            for (int k = 0; k < s; ++k) {
                const float Lkk = sL[(k * S1 + k) * G + gq];
                float tk = (Lkk > 1e-20f) ? (rhs - acc) / Lkk : 0.f;
                tk = __shfl(tk, k);
                if (rr == k) trr = tk;
                if (rr > k && rr < s)
                    acc = fmaf(sL[(rr * S1 + k) * G + gq], tk, acc);
            }
            // backward solve L^T chat = t
            float crr = 0.f;
            acc = 0.f;
            for (int k = s - 1; k >= 0; --k) {
                const float Lkk = sL[(k * S1 + k) * G + gq];
                float ck = (Lkk > 1e-20f) ? (trr - acc) / Lkk : 0.f;
                ck = __shfl(ck, k);
                if (rr == k) crr = ck;
                if (rr < k) acc = fmaf(sL[(k * S1 + rr) * G + gq], ck, acc);
            }
            if (rr < s) sD[rr * G + gq] = crr * invn_r;   // c_i on raw k_i
        }
        __syncthreads();   // c visible

        // ---- update: w += sum c_i k_i ----
        for (int i = 0; i < s; ++i)
            wsol = fmaf(sD[i * G + g], sK[(i * G + g) * VS + c], wsol);
        __syncthreads();   // reads done before next sweep overwrites
    }

    if (alive) out[sys * N + c] = 2.f * wsol - v_own;
}

extern "C" void kernel_launch(void* const* d_in, const int* in_sizes, int n_in,
                              void* d_out, int out_size, void* d_ws, size_t ws_size,
                              hipStream_t stream) {
    const float* x = (const float*)d_in[0];   // (B*T, 256)
    const float* P = (const float*)d_in[1];   // skew_param (256,256)
    const float* v = (const float*)d_in[2];   // (1,256)
    float* out = (float*)d_out;
    const int batch = in_sizes[0] / N;        // B*T

    const int nblk = (batch + G - 1) / G;
    hipLaunchKernelGGL(cayley_v13, dim3(nblk), dim3(BLK), 0, stream, x, P, v, out, batch);
}